// Round 9
// baseline (159.959 us; speedup 1.0000x reference)
//
#include <hip/hip_runtime.h>
#include <hip/hip_bf16.h>

#define DEV static __device__ __forceinline__

typedef __attribute__((ext_vector_type(8))) short short8;
typedef __attribute__((ext_vector_type(4))) short short4v;
typedef __attribute__((ext_vector_type(4))) float float4v;
typedef __attribute__((ext_vector_type(4))) int int4v;

DEV unsigned short f2bf(float f) {
  unsigned int u = __builtin_bit_cast(unsigned int, f);
  u = (u + 0x7fffu + ((u >> 16) & 1u)) >> 16;
  return (unsigned short)u;
}

DEV __attribute__((address_space(3))) void* to_lds(void* p) {
  return (__attribute__((address_space(3))) void*)p;
}
DEV const __attribute__((address_space(1))) void* to_glb(const void* p) {
  return (const __attribute__((address_space(1))) void*)p;
}

DEV float4v zero4() { float4v z = {0.f, 0.f, 0.f, 0.f}; return z; }

DEV float ex2(float x) {
  float r;
  asm("v_exp_f32 %0, %1" : "=v"(r) : "v"(x));
  return r;
}
DEV unsigned int cvtpk(float lo, float hi) {
  unsigned int r;
  asm("v_cvt_pk_bf16_f32 %0, %1, %2" : "=v"(r) : "v"(lo), "v"(hi));
  return r;
}

// ---------------------------------------------------------------- convert
__global__ __launch_bounds__(256)
void f32_to_bf16_kn(const float* __restrict__ src, unsigned short* __restrict__ dst, int n) {
  int i = (blockIdx.x * blockDim.x + threadIdx.x) * 4;
  int stride = gridDim.x * blockDim.x * 4;
  for (; i < n; i += stride) {
    float4v v = *reinterpret_cast<const float4v*>(src + i);
    short4v o;
    o[0] = (short)f2bf(v[0]);
    o[1] = (short)f2bf(v[1]);
    o[2] = (short)f2bf(v[2]);
    o[3] = (short)f2bf(v[3]);
    *reinterpret_cast<short4v*>(dst + i) = o;
  }
}

// ---------------------------------------------------------------- 8-phase GEMM
// C[m,n] = sum_k A[m,k]*B[n,k] + bias[n]. BM=256, BN=NF*64, BK=64, 8 waves
// (2x4), wave = 128 x NF*16. Iter = 2 K-tiles, 8 phases; per phase:
// {ds_read subtile | stage 1-2 passes | vmcnt(N) | barrier | lgkm | 12*MFMA |
// barrier}. Counted vmcnt cycle [4,5,6,3] (derived from in-order retirement;
// loads never drain to 0 in the main loop). A staged in phase-aligned 64-row
// slices ([32q,+32) u [128+32q,+32)); B staged whole (read at tile phase 0).
// EPI==1: f32 out + bias. EPI==2: qkv split epilogue.
template<int NF, int EPI>
DEV void gemm8p_body(const unsigned short* __restrict__ A, const unsigned short* __restrict__ B,
                     const float* __restrict__ bias, void* __restrict__ Cout,
                     unsigned short* __restrict__ vtout, int M, int N, int K,
                     unsigned short* sA, unsigned short* sB) {
  constexpr int BN = NF * 64;
  const int t = threadIdx.x, lane = t & 63, wid = t >> 6;
  const int l15 = lane & 15, l4 = lane >> 4;
  const int wm = wid >> 2, wn = wid & 3;
  const int wrow = wm * 128, wcol = wn * NF * 16;
  const int gx = gridDim.x, nwg = gx * gridDim.y;
  const int lid = blockIdx.y * gx + blockIdx.x;
  const int swz = (lid & 7) * (nwg >> 3) + (lid >> 3);  // nwg % 8 == 0
  const int m0 = (swz / gx) * 256, n0 = (swz % gx) * BN;
  const int lkey = (l15 & 7) << 4;

  float4v acc[8][NF];
#pragma unroll
  for (int i = 0; i < 8; i++)
#pragma unroll
    for (int j = 0; j < NF; j++) acc[i][j] = zero4();

  auto stB = [&](int buf, int k0, int pass) {
    int u = t + pass * 512, row = u >> 3, sl = u & 7;
    const unsigned short* g = &B[(size_t)(n0 + row) * K + k0 + (sl ^ (row & 7)) * 8];
    __builtin_amdgcn_global_load_lds(to_glb(g), to_lds(&sB[buf * BN * 64 + u * 8]), 16, 0, 0);
  };
  auto stA = [&](int buf, int k0, int q) {  // 64-row slice q: [32q,+32)u[128+32q,+32)
    int r6 = t >> 3, sl = t & 7;
    int row = 32 * q + (r6 & 31) + 128 * (r6 >> 5);
    const unsigned short* g = &A[(size_t)(m0 + row) * K + k0 + (sl ^ (row & 7)) * 8];
    __builtin_amdgcn_global_load_lds(to_glb(g), to_lds(&sA[buf * 256 * 64 + row * 64 + sl * 8]), 16, 0, 0);
  };
  short8 af[2][2], bfr[NF][2];
  auto rdA = [&](const char* Ab, int q) {
#pragma unroll
    for (int fi = 0; fi < 2; fi++)
#pragma unroll
      for (int kc = 0; kc < 2; kc++) {
        int off = ((wrow + (q * 2 + fi) * 16 + l15) * 128 + kc * 64 + l4 * 16) ^ lkey;
        af[fi][kc] = *reinterpret_cast<const short8*>(Ab + off);
      }
  };
  auto rdB = [&](const char* Bb) {
#pragma unroll
    for (int nf = 0; nf < NF; nf++)
#pragma unroll
      for (int kc = 0; kc < 2; kc++) {
        int off = ((wcol + nf * 16 + l15) * 128 + kc * 64 + l4 * 16) ^ lkey;
        bfr[nf][kc] = *reinterpret_cast<const short8*>(Bb + off);
      }
  };

#define MMQ(Q)                                                                           \
  do {                                                                                   \
    __builtin_amdgcn_s_setprio(1);                                                       \
    _Pragma("unroll") for (int kc = 0; kc < 2; kc++)                                     \
        _Pragma("unroll") for (int fi = 0; fi < 2; fi++)                                 \
            _Pragma("unroll") for (int nf = 0; nf < NF; nf++) acc[(Q)*2 + fi][nf] =      \
        __builtin_amdgcn_mfma_f32_16x16x32_bf16(af[fi][kc], bfr[nf][kc],                 \
                                                acc[(Q)*2 + fi][nf], 0, 0, 0);           \
    __builtin_amdgcn_s_setprio(0);                                                       \
  } while (0)
#define BARR __builtin_amdgcn_s_barrier()
#define LGKM0 asm volatile("s_waitcnt lgkmcnt(0)" ::: "memory")
#define VMW(N) asm volatile("s_waitcnt vmcnt(" #N ")" ::: "memory")

  // prologue: tile 0 -> buf0 (order: B passes then A slices — vmcnt counts rely on it)
#pragma unroll
  for (int p = 0; p < NF; p++) stB(0, 0, p);
#pragma unroll
  for (int q = 0; q < 4; q++) stA(0, 0, q);
  VMW(3);
  BARR;

  const char* Ab0 = (const char*)&sA[0];
  const char* Bb0 = (const char*)&sB[0];
  const char* Ab1 = (const char*)&sA[256 * 64];
  const char* Bb1 = (const char*)&sB[BN * 64];
  const int NI = K >> 7;

  for (int i = 0; i < NI; ++i) {
    const int k1 = (i << 7) + 64, k2 = (i << 7) + 128;
    const bool nl = (i + 1 < NI);
    // ---- tile t0 = 2i (buf0); stage tile 2i+1 -> buf1
    // ph1
    rdB(Bb0);
    rdA(Ab0, 0);
    stB(1, k1, 0);
    stB(1, k1, 1);
    VMW(4);
    BARR; LGKM0; MMQ(0); BARR;
    // ph2
    rdA(Ab0, 1);
    if (NF == 3) { stB(1, k1, 2); stA(1, k1, 0); }
    else { stA(1, k1, 0); stA(1, k1, 1); }
    VMW(5);
    BARR; LGKM0; MMQ(1); BARR;
    // ph3
    rdA(Ab0, 2);
    if (NF == 3) { stA(1, k1, 1); stA(1, k1, 2); }
    else { stA(1, k1, 2); stA(1, k1, 3); }
    VMW(6);
    BARR; LGKM0; MMQ(2); BARR;
    // ph4
    rdA(Ab0, 3);
    if (NF == 3) stA(1, k1, 3);
    VMW(3);
    BARR; LGKM0; MMQ(3); BARR;
    // ---- tile t1 = 2i+1 (buf1); stage tile 2i+2 -> buf0 (if exists)
    // ph5
    rdB(Bb1);
    rdA(Ab1, 0);
    if (nl) { stB(0, k2, 0); stB(0, k2, 1); VMW(4); } else { VMW(2); }
    BARR; LGKM0; MMQ(0); BARR;
    // ph6
    rdA(Ab1, 1);
    if (nl) {
      if (NF == 3) { stB(0, k2, 2); stA(0, k2, 0); }
      else { stA(0, k2, 0); stA(0, k2, 1); }
      VMW(5);
    } else { VMW(1); }
    BARR; LGKM0; MMQ(1); BARR;
    // ph7
    rdA(Ab1, 2);
    if (nl) {
      if (NF == 3) { stA(0, k2, 1); stA(0, k2, 2); }
      else { stA(0, k2, 2); stA(0, k2, 3); }
      VMW(6);
    } else { VMW(0); }
    BARR; LGKM0; MMQ(2); BARR;
    // ph8
    rdA(Ab1, 3);
    if (nl) {
      if (NF == 3) stA(0, k2, 3);
      VMW(3);
    }
    BARR; LGKM0; MMQ(3); BARR;
  }
#undef MMQ
#undef BARR
#undef LGKM0
#undef VMW

  // epilogue C-write
#pragma unroll
  for (int mf = 0; mf < 8; mf++) {
    const int row0 = m0 + wrow + mf * 16 + l4 * 4;
#pragma unroll
    for (int nf = 0; nf < NF; nf++) {
      const int col = n0 + wcol + nf * 16 + l15;
      float vv[4];
#pragma unroll
      for (int r = 0; r < 4; r++) vv[r] = acc[mf][nf][r] + bias[col];
      if (EPI == 1) {
#pragma unroll
        for (int r = 0; r < 4; r++)
          ((float*)Cout)[(size_t)(row0 + r) * N + col] = vv[r];
      } else {
        if (col < 2048) {
          const float sc = (col < 1024) ? 0.18033688f : 1.0f;  // 0.125*log2(e) on q
#pragma unroll
          for (int r = 0; r < 4; r++)
            ((unsigned short*)Cout)[(size_t)(row0 + r) * 2048 + col] = f2bf(vv[r] * sc);
        } else {
          const int hv = col - 2048;
          const int R = ((row0 >> 11) * 16 + (hv >> 6)) * 64 + (hv & 63);
          const int tc = row0 & 2047;
          unsigned long long w = (unsigned long long)cvtpk(vv[0], vv[1]) |
                                 ((unsigned long long)cvtpk(vv[2], vv[3]) << 32);
          *(unsigned long long*)&vtout[(size_t)R * 2048 + tc] = w;
        }
      }
    }
  }
}

// QKV: BN=192, split epilogue
__global__ __launch_bounds__(512, 2)
void gemm8p_qkv_kn(const unsigned short* __restrict__ A, const unsigned short* __restrict__ B,
                   const float* __restrict__ bias, unsigned short* __restrict__ qkout,
                   unsigned short* __restrict__ vtout, int M, int N, int K) {
  __shared__ unsigned short sA[2 * 256 * 64];
  __shared__ unsigned short sB[2 * 192 * 64];
  gemm8p_body<3, 2>(A, B, bias, qkout, vtout, M, N, K, sA, sB);
}

// proj: BN=128, f32 out
__global__ __launch_bounds__(512, 2)
void gemm8p_proj_kn(const unsigned short* __restrict__ A, const unsigned short* __restrict__ B,
                    const float* __restrict__ bias, float* __restrict__ Cout,
                    int M, int N, int K) {
  __shared__ unsigned short sA[2 * 256 * 64];
  __shared__ unsigned short sB[2 * 128 * 64];
  gemm8p_body<2, 1>(A, B, bias, Cout, nullptr, M, N, K, sA, sB);
}

// ---------------------------------------------------------------- attention
// (unchanged) 128-q blocks (4 waves x 32 q), static softmax in log2 units,
// K and V^T staged via linear global_load_lds, l via ones-MFMA.
__global__ __launch_bounds__(256, 3)
void attn_kn(const unsigned short* __restrict__ qk, const unsigned short* __restrict__ vt,
             unsigned short* __restrict__ y) {
  __shared__ unsigned short sK[2][4096];  // [64 kv][64 d], key (kv&7)<<4
  __shared__ unsigned short sV[2][4096];  // [64 d][64 kv], key (d&7)<<4
  __shared__ unsigned short sP[4][2048];  // per-wave [32 q][64 kv], key (q&7)<<4
  const int t = threadIdx.x;
  const int wave = t >> 6, lane = t & 63;
  const int l15 = lane & 15, l4 = lane >> 4;
  const int bh = blockIdx.x, b = bh >> 4, h = bh & 15;
  const int yb_ = blockIdx.y;
  const int qt = ((yb_ >> 2) & 1) ? ((yb_ < 8) ? yb_ + 4 : yb_ - 12) : 15 - yb_;
  const int q0w = qt * 128 + wave * 32;
  const size_t base = (size_t)b * 2048 * 2048;
  const unsigned short* Qp = qk + base + h * 64;
  const unsigned short* Kp = Qp + 1024;
  const unsigned short* Vt = vt + (size_t)bh * 64 * 2048;
  unsigned short* yb = y + (size_t)b * 2048 * 1024 + h * 64;

  short8 ones8;
#pragma unroll
  for (int j = 0; j < 8; j++) ones8[j] = (short)0x3F80;

  short8 qf[2][2];
#pragma unroll
  for (int m = 0; m < 2; m++)
#pragma unroll
    for (int kc = 0; kc < 2; kc++)
      qf[m][kc] = *reinterpret_cast<const short8*>(
          &Qp[(size_t)(q0w + m * 16 + l15) * 2048 + kc * 32 + l4 * 8]);

  float4v o_acc[2][4];
#pragma unroll
  for (int m = 0; m < 2; m++)
#pragma unroll
    for (int f = 0; f < 4; f++) o_acc[m][f] = zero4();
  float4v acc_l[2] = {zero4(), zero4()};

  auto stage_k = [&](int kv0, int bi) {
#pragma unroll
    for (int i = 0; i < 2; i++) {
      int unit = t + i * 256;
      int row = unit >> 3, sl = unit & 7;
      const unsigned short* g = Kp + (size_t)(kv0 + row) * 2048 + (sl ^ (row & 7)) * 8;
      __builtin_amdgcn_global_load_lds(to_glb(g), to_lds(&sK[bi][unit * 8]), 16, 0, 0);
    }
  };
  auto stage_v = [&](int kv0, int bi) {
#pragma unroll
    for (int i = 0; i < 2; i++) {
      int unit = t + i * 256;
      int d = unit >> 3, sl = unit & 7;
      const unsigned short* g = Vt + (size_t)d * 2048 + kv0 + (sl ^ (d & 7)) * 8;
      __builtin_amdgcn_global_load_lds(to_glb(g), to_lds(&sV[bi][unit * 8]), 16, 0, 0);
    }
  };

  const int nt = 2 * qt + 2;
  stage_k(0, 0);
  stage_v(0, 0);
  __syncthreads();

  for (int ti = 0; ti < nt; ti++) {
    const int cur = ti & 1;
    const int kv0 = ti * 64;
    const bool last = (ti + 1 == nt);
    if (!last) { stage_k(kv0 + 64, cur ^ 1); stage_v(kv0 + 64, cur ^ 1); }

    if (kv0 <= q0w + 31) {
      const char* Kb = (const char*)sK[cur];
      const char* Vb = (const char*)sV[cur];
      char* Pb = (char*)sP[wave];

      float4v st[2][4];
#pragma unroll
      for (int m = 0; m < 2; m++)
#pragma unroll
        for (int c = 0; c < 4; c++) st[m][c] = zero4();
#pragma unroll
      for (int kc = 0; kc < 2; kc++) {
        short8 ka[4];
#pragma unroll
        for (int c = 0; c < 4; c++) {
          int off = ((c * 16 + l15) * 128 + kc * 64 + l4 * 16) ^ ((l15 & 7) << 4);
          ka[c] = *reinterpret_cast<const short8*>(Kb + off);
        }
        __builtin_amdgcn_s_setprio(1);
#pragma unroll
        for (int c = 0; c < 4; c++) {
          st[0][c] = __builtin_amdgcn_mfma_f32_16x16x32_bf16(ka[c], qf[0][kc], st[0][c], 0, 0, 0);
          st[1][c] = __builtin_amdgcn_mfma_f32_16x16x32_bf16(ka[c], qf[1][kc], st[1][c], 0, 0, 0);
        }
        __builtin_amdgcn_s_setprio(0);
      }

#pragma unroll
      for (int m = 0; m < 2; m++) {
        if (kv0 + 63 > q0w + m * 16) {
          const int qrow = q0w + m * 16 + l15;
#pragma unroll
          for (int c = 0; c < 4; c++)
#pragma unroll
            for (int r = 0; r < 4; r++) {
              int kv = kv0 + c * 16 + l4 * 4 + r;
              if (kv > qrow) st[m][c][r] = -1e30f;
            }
        }
#pragma unroll
        for (int c = 0; c < 4; c++) {
          float p0 = ex2(st[m][c][0]), p1 = ex2(st[m][c][1]);
          float p2 = ex2(st[m][c][2]), p3 = ex2(st[m][c][3]);
          unsigned long long w = (unsigned long long)cvtpk(p0, p1) |
                                 ((unsigned long long)cvtpk(p2, p3) << 32);
          int off = ((m * 16 + l15) * 128 + (c * 16 + l4 * 4) * 2) ^ ((l15 & 7) << 4);
          *(unsigned long long*)(Pb + off) = w;
        }
      }
      asm volatile("s_waitcnt lgkmcnt(0)" ::: "memory");
      __builtin_amdgcn_sched_barrier(0);

#pragma unroll
      for (int kc = 0; kc < 2; kc++) {
        short8 pa[2];
#pragma unroll
        for (int m = 0; m < 2; m++) {
          int off = ((m * 16 + l15) * 128 + kc * 64 + l4 * 16) ^ ((l15 & 7) << 4);
          pa[m] = *reinterpret_cast<const short8*>(Pb + off);
        }
        short8 vbf[4];
#pragma unroll
        for (int f = 0; f < 4; f++) {
          int d = f * 16 + l15;
          int off = (d * 128 + kc * 64 + l4 * 16) ^ ((d & 7) << 4);
          vbf[f] = *reinterpret_cast<const short8*>(Vb + off);
        }
        __builtin_amdgcn_s_setprio(1);
#pragma unroll
        for (int f = 0; f < 4; f++) {
          o_acc[0][f] = __builtin_amdgcn_mfma_f32_16x16x32_bf16(pa[0], vbf[f], o_acc[0][f], 0, 0, 0);
          o_acc[1][f] = __builtin_amdgcn_mfma_f32_16x16x32_bf16(pa[1], vbf[f], o_acc[1][f], 0, 0, 0);
        }
        acc_l[0] = __builtin_amdgcn_mfma_f32_16x16x32_bf16(pa[0], ones8, acc_l[0], 0, 0, 0);
        acc_l[1] = __builtin_amdgcn_mfma_f32_16x16x32_bf16(pa[1], ones8, acc_l[1], 0, 0, 0);
        __builtin_amdgcn_s_setprio(0);
      }
    }
    __syncthreads();
  }

#pragma unroll
  for (int m = 0; m < 2; m++) {
    float lr[4];
#pragma unroll
    for (int r = 0; r < 4; r++) lr[r] = 1.0f / acc_l[m][r];
#pragma unroll
    for (int f = 0; f < 4; f++)
#pragma unroll
      for (int r = 0; r < 4; r++) {
        int q = q0w + m * 16 + l4 * 4 + r;
        yb[(size_t)q * 1024 + f * 16 + l15] = f2bf(o_acc[m][f][r] * lr[r]);
      }
  }
}

// ---------------------------------------------------------------- launch
extern "C" void kernel_launch(void* const* d_in, const int* in_sizes, int n_in,
                              void* d_out, int out_size, void* d_ws, size_t ws_size,
                              hipStream_t stream) {
  const float* x = (const float*)d_in[0];
  const float* w_qkv = (const float*)d_in[1];
  const float* b_qkv = (const float*)d_in[2];
  const float* w_proj = (const float*)d_in[3];
  const float* b_proj = (const float*)d_in[4];
  float* out = (float*)d_out;
  char* ws = (char*)d_ws;

  const int M = 4 * 2048;
  unsigned short* x_bf = (unsigned short*)ws;                        // 16 MB
  unsigned short* wqkv_bf = (unsigned short*)(ws + (22ull << 20));   // 6 MB
  unsigned short* wproj_bf = (unsigned short*)(ws + (28ull << 20));  // 2 MB
  unsigned short* qk_buf = (unsigned short*)(ws + (30ull << 20));    // 32 MB [8192][2048]
  unsigned short* vt = (unsigned short*)(ws + (62ull << 20));        // 16 MB [4096][2048]
  unsigned short* y_bf = x_bf;  // reuse x region after QKV GEMM

  f32_to_bf16_kn<<<2048, 256, 0, stream>>>(x, x_bf, M * 1024);
  f32_to_bf16_kn<<<1024, 256, 0, stream>>>(w_qkv, wqkv_bf, 3072 * 1024);
  f32_to_bf16_kn<<<512, 256, 0, stream>>>(w_proj, wproj_bf, 1024 * 1024);

  // QKV: 256x192 tiles -> 16 x 32 = 512 blocks (exactly 2 balanced rounds)
  gemm8p_qkv_kn<<<dim3(16, 32), 512, 0, stream>>>(
      x_bf, wqkv_bf, b_qkv, qk_buf, vt, M, 3072, 1024);

  attn_kn<<<dim3(64, 16), 256, 0, stream>>>(qk_buf, vt, y_bf);

  // proj: 256x128 tiles -> 8 x 32 = 256 blocks (1 round)
  gemm8p_proj_kn<<<dim3(8, 32), 512, 0, stream>>>(
      y_bf, wproj_bf, b_proj, out, M, 1024, 1024);
}